// Round 5
// baseline (205.656 us; speedup 1.0000x reference)
//
#include <hip/hip_runtime.h>
#include <hip/hip_bf16.h>

using bf16 = __hip_bfloat16;
typedef __attribute__((ext_vector_type(8))) short bf16x8;
typedef __attribute__((ext_vector_type(4))) short bf16x4;
typedef __attribute__((ext_vector_type(4))) float f32x4;
typedef __attribute__((ext_vector_type(16))) float f32x16;

static constexpr int Bb = 4, Ss = 2048, Dd = 1024, Hh = 16, HD = 64;
static constexpr int TD = 3 * Dd;            // 3072
static constexpr int Mrows = Bb * Ss;        // 8192

#define MFMA16(a, b, c) __builtin_amdgcn_mfma_f32_16x16x32_bf16((a), (b), (c), 0, 0, 0)
#define MFMA32(a, b, c) __builtin_amdgcn_mfma_f32_32x32x16_bf16((a), (b), (c), 0, 0, 0)

__device__ __forceinline__ void gload_lds16(const void* g, void* l) {
    __builtin_amdgcn_global_load_lds(
        (const __attribute__((address_space(1))) void*)g,
        (__attribute__((address_space(3))) void*)l, 16, 0, 0);
}

__device__ __forceinline__ unsigned lds_addr(const void* p) {
    return (unsigned)(unsigned long long)(const __attribute__((address_space(3))) char*)p;
}

__device__ __forceinline__ unsigned pack2bf(float a, float b) {
    bf16 x = __float2bfloat16(a), y = __float2bfloat16(b);
    return (unsigned)(*(unsigned short*)&x) | ((unsigned)(*(unsigned short*)&y) << 16);
}

// ---------------- cast fp32 -> bf16, 4 elems/thread ----------------
__global__ void cast_f32_bf16(const float* __restrict__ in, bf16* __restrict__ out, int n4) {
    int i = blockIdx.x * blockDim.x + threadIdx.x;
    if (i >= n4) return;
    float4 v = ((const float4*)in)[i];
    bf16 t0 = __float2bfloat16(v.x), t1 = __float2bfloat16(v.y);
    bf16 t2 = __float2bfloat16(v.z), t3 = __float2bfloat16(v.w);
    unsigned int lo = (unsigned int)(*(unsigned short*)&t0) | ((unsigned int)(*(unsigned short*)&t1) << 16);
    unsigned int hi = (unsigned int)(*(unsigned short*)&t2) | ((unsigned int)(*(unsigned short*)&t3) << 16);
    uint2 o; o.x = lo; o.y = hi;
    *(uint2*)(out + 4l * i) = o;
}

// ---------------- GEMM: C[m,n] = sum_k A[m,k] * Bt[n,k] ----------------
// 128x128 tile, BK=32, 4 waves. XCD-aware bijective block swizzle (T1).
template<bool OUT_BF16>
__global__ __launch_bounds__(256, 2) void gemm_bt(
    const bf16* __restrict__ A, const bf16* __restrict__ Bt,
    bf16* __restrict__ Cb, float* __restrict__ Cf, const float* __restrict__ bias,
    int M, int N, int K)
{
    __shared__ __align__(16) bf16 As[128 * 32];
    __shared__ __align__(16) bf16 Bs[128 * 32];
    const int tid = threadIdx.x;
    const int lane = tid & 63, wid = tid >> 6;
    const int lc = lane & 15, lg = lane >> 4;
    const int wr = wid >> 1, wc = wid & 1;

    const int nwg = gridDim.x * gridDim.y;
    int orig = blockIdx.y * gridDim.x + blockIdx.x;
    int swz = orig;
    if ((nwg & 7) == 0) swz = (orig & 7) * (nwg >> 3) + (orig >> 3);
    const long tile_m = (long)(swz / (int)gridDim.x) * 128;
    const long tile_n = (long)(swz % (int)gridDim.x) * 128;

    const f32x4 fz = {0.f, 0.f, 0.f, 0.f};
    f32x4 acc[4][4];
#pragma unroll
    for (int i = 0; i < 4; ++i)
#pragma unroll
        for (int j = 0; j < 4; ++j) acc[i][j] = fz;

    for (int k0 = 0; k0 < K; k0 += 32) {
#pragma unroll
        for (int it = 0; it < 2; ++it) {
            int c = tid + it * 256;
            int row = c >> 2, seg = c & 3;
            gload_lds16(A  + (tile_m + row) * (long)K + k0 + seg * 8, (char*)As + c * 16);
            gload_lds16(Bt + (tile_n + row) * (long)K + k0 + seg * 8, (char*)Bs + c * 16);
        }
        __syncthreads();
        bf16x8 af[4], bfr[4];
#pragma unroll
        for (int i = 0; i < 4; ++i) {
            af[i]  = *(const bf16x8*)(As + (wr * 64 + i * 16 + lc) * 32 + lg * 8);
            bfr[i] = *(const bf16x8*)(Bs + (wc * 64 + i * 16 + lc) * 32 + lg * 8);
        }
#pragma unroll
        for (int i = 0; i < 4; ++i)
#pragma unroll
            for (int j = 0; j < 4; ++j)
                acc[i][j] = MFMA16(af[i], bfr[j], acc[i][j]);
        __syncthreads();
    }
#pragma unroll
    for (int i = 0; i < 4; ++i)
#pragma unroll
        for (int j = 0; j < 4; ++j)
#pragma unroll
            for (int r = 0; r < 4; ++r) {
                long row = tile_m + wr * 64 + i * 16 + lg * 4 + r;
                long col = tile_n + wc * 64 + j * 16 + lc;
                float v = acc[i][j][r];
                if constexpr (OUT_BF16) Cb[row * N + col] = __float2bfloat16(v);
                else                    Cf[row * N + col] = v + bias[col];
            }
}

// ---------------- causal flash attention v4b ----------------
// grid: (16 pairs, B*H), 4 waves. Strips (p, 31-p) of 64 q-rows; waves 0,1 ->
// long strip, waves 2,3 -> short strip; 32 q-rows/wave. Swapped QK^T (32x32),
// in-reg softmax, permlane P-exchange, V via ds_read_b64_tr_b16, defer-max.
// K/V staged by global_load_lds (pre-swizzled source, linear LDS dest),
// double-buffered, 1 barrier/tile. launch_bounds (256,2): no VGPR cap at 128 —
// spilling an in-flight tr-read dest corrupts data (round-4 lesson).
__global__ __launch_bounds__(256, 2) void attn_fwd4(const bf16* __restrict__ qkv,
                                                    bf16* __restrict__ out) {
    const int p  = blockIdx.x;                 // 0..15
    const int bh = blockIdx.y;                 // 0..63
    const int b = bh >> 4, h = bh & 15;
    const int tid = threadIdx.x;
    const int lane = tid & 63, wid = tid >> 6;
    const int ln31 = lane & 31, hi = lane >> 5;
    const int ch = (lane >> 4) & 1, c16 = lane & 15;
    const long rowbase = (long)b * Ss;
    const int strip = (wid < 2) ? (31 - p) : p;
    const int q0 = strip * 64 + (wid & 1) * 32;   // this wave's 32 q-rows
    const int nt = 32 - p;                        // tiles for the long strip
    const float CL2 = 0.18033688f;                // 0.125 * log2(e)

    __shared__ __align__(16) bf16 Ks[2][64 * 64];
    __shared__ __align__(16) bf16 Vs[2][64 * 64];

    // ---- staging: global_load_lds, LDS linear in slot s, source pre-swizzled.
    // K: slot s holds K[r=s>>3][sg*8..], sg = (s&7)^(r&7)  (XOR row swizzle)
    // V: slot s holds V[r][sg*8..], r = (s>>5)*4|((s>>1)&3), sg = ((s>>3)&3)*2|(s&1)
    const int sK0 = tid, sK1 = tid + 256;
    const int rK0 = sK0 >> 3, cK0 = ((sK0 & 7) ^ (rK0 & 7)) * 8;
    const int rK1 = sK1 >> 3, cK1 = ((sK1 & 7) ^ (rK1 & 7)) * 8;
    const int rV0 = ((sK0 >> 5) << 2) | ((sK0 >> 1) & 3);
    const int cV0 = ((((sK0 >> 3) & 3) << 1) | (sK0 & 1)) * 8;
    const int rV1 = ((sK1 >> 5) << 2) | ((sK1 >> 1) & 3);
    const int cV1 = ((((sK1 >> 3) & 3) << 1) | (sK1 & 1)) * 8;
    const bf16* gK0 = qkv + (rowbase + rK0) * (long)TD + h * HD + Dd + cK0;
    const bf16* gK1 = qkv + (rowbase + rK1) * (long)TD + h * HD + Dd + cK1;
    const bf16* gV0 = qkv + (rowbase + rV0) * (long)TD + h * HD + 2 * Dd + cV0;
    const bf16* gV1 = qkv + (rowbase + rV1) * (long)TD + h * HD + 2 * Dd + cV1;

    auto STAGE = [&](int buf, int kt) {
        const long o = (long)kt * 64 * TD;
        gload_lds16(gK0 + o, (char*)Ks[buf] + tid * 16);
        gload_lds16(gK1 + o, (char*)Ks[buf] + 4096 + tid * 16);
        gload_lds16(gV0 + o, (char*)Vs[buf] + tid * 16);
        gload_lds16(gV1 + o, (char*)Vs[buf] + 4096 + tid * 16);
    };

    // Q fragments (B-operand of 32x32x16): qa[dk][i] = Q[q0+ln31][dk*16+hi*8+i]
    bf16x8 qa[4];
#pragma unroll
    for (int dk = 0; dk < 4; ++dk)
        qa[dk] = *(const bf16x8*)(qkv + (rowbase + q0 + ln31) * (long)TD + h * HD + dk * 16 + hi * 8);

    f32x16 acc[2];                             // acc[dt]: O[q=crow(r,hi)][dt*32+ln31]
#pragma unroll
    for (int dt = 0; dt < 2; ++dt) acc[dt] = (f32x16)0.0f;
    float m2 = -3.0e38f;                       // running max, log2 units
    float l = 0.f;

    STAGE(0, 0);
    __syncthreads();

    for (int kt = 0; kt < nt; ++kt) {
        const int cur = kt & 1;
        if (kt + 1 < nt) STAGE(cur ^ 1, kt + 1);

        if (kt * 64 <= q0 + 31) {
            const char* kbp = (const char*)Ks[cur];
            const char* vbp = (const char*)Vs[cur];
            // ---- QK^T swapped: sc[st][r] = S^T[k=kt*64+st*32+crow(r,hi)][q=q0+ln31]
            f32x16 sc[2];
#pragma unroll
            for (int st = 0; st < 2; ++st) {
                f32x16 z = (f32x16)0.0f;
                const int row = st * 32 + ln31;
                const int sw = (row & 7) << 4;
#pragma unroll
                for (int dk = 0; dk < 4; ++dk) {
                    bf16x8 ka = *(const bf16x8*)(kbp + ((row * 128 + dk * 32 + hi * 16) ^ sw));
                    z = MFMA32(ka, qa[dk], z);
                }
                sc[st] = z;
            }
            // ---- causal mask (diag tile only) ----
            if (kt * 64 + 63 > q0) {
                const int qg = q0 + ln31;
                const int kb = kt * 64 + 4 * hi;
#pragma unroll
                for (int st = 0; st < 2; ++st)
#pragma unroll
                    for (int r = 0; r < 16; ++r) {
                        int kg = kb + st * 32 + (r & 3) + 8 * (r >> 2);
                        if (kg > qg) sc[st][r] = -3.0e38f;
                    }
            }
            // ---- row max ----
            float mx = sc[0][0];
#pragma unroll
            for (int r = 1; r < 16; ++r) mx = fmaxf(mx, sc[0][r]);
#pragma unroll
            for (int r = 0; r < 16; ++r) mx = fmaxf(mx, sc[1][r]);
            mx = fmaxf(mx, __shfl_xor(mx, 32));
            float pmax2 = mx * CL2;
            // ---- defer-max rescale (rare) ----
            if (__ballot(pmax2 > m2 + 8.0f)) {
                float mnew = fmaxf(m2, pmax2);
                float sf = __builtin_amdgcn_exp2f(m2 - mnew);
                m2 = mnew;
                l *= sf;
#pragma unroll
                for (int r = 0; r < 16; ++r) {
                    float sfr = __shfl(sf, (r & 3) + 8 * (r >> 2) + 4 * hi);
                    acc[0][r] *= sfr;
                    acc[1][r] *= sfr;
                }
            }
            // ---- issue all 16 V tr-reads early ----
            bf16x4 vl[4][2], vh[4][2];
            const unsigned vbase = lds_addr(vbp) + hi * 1024 + ch * 128 + c16 * 8;
#pragma unroll
            for (int ksg = 0; ksg < 4; ++ksg)
#pragma unroll
                for (int dt = 0; dt < 2; ++dt) {
                    asm volatile("ds_read_b64_tr_b16 %0, %2\n\t"
                                 "ds_read_b64_tr_b16 %1, %2 offset:512"
                                 : "=v"(vl[ksg][dt]), "=v"(vh[ksg][dt])
                                 : "v"(vbase + (unsigned)(ksg * 2048 + dt * 256)) : "memory");
                }
            // ---- exp + row-sum + pack ----
            const float mt = m2;
            float sum = 0.f;
            unsigned w[2][8];
#pragma unroll
            for (int st = 0; st < 2; ++st)
#pragma unroll
                for (int n = 0; n < 8; ++n) {
                    float e0 = __builtin_amdgcn_exp2f(fmaf(sc[st][2 * n],     CL2, -mt));
                    float e1 = __builtin_amdgcn_exp2f(fmaf(sc[st][2 * n + 1], CL2, -mt));
                    sum += e0 + e1;
                    w[st][n] = pack2bf(e0, e1);
                }
            sum += __shfl_xor(sum, 32);
            l += sum;
            // ---- P exchange: 8 permlane32_swap ----
            union { unsigned u[4]; bf16x8 v; } pa[4];
#pragma unroll
            for (int ksg = 0; ksg < 4; ++ksg) {
                const int st = ksg >> 1, kl = ksg & 1;
                unsigned x0 = w[st][4 * kl],     y0 = w[st][4 * kl + 2];
                unsigned x1 = w[st][4 * kl + 1], y1 = w[st][4 * kl + 3];
                asm volatile("v_permlane32_swap_b32 %0, %1" : "+v"(x0), "+v"(y0));
                asm volatile("v_permlane32_swap_b32 %0, %1" : "+v"(x1), "+v"(y1));
                pa[ksg].u[0] = x0; pa[ksg].u[1] = x1; pa[ksg].u[2] = y0; pa[ksg].u[3] = y1;
            }
            // ---- PV ----
            asm volatile("s_waitcnt lgkmcnt(0)" ::: "memory");
            __builtin_amdgcn_sched_barrier(0);
#pragma unroll
            for (int ksg = 0; ksg < 4; ++ksg)
#pragma unroll
                for (int dt = 0; dt < 2; ++dt) {
                    bf16x8 vb = __builtin_shufflevector(vl[ksg][dt], vh[ksg][dt],
                                                        0, 1, 2, 3, 4, 5, 6, 7);
                    acc[dt] = MFMA32(pa[ksg].v, vb, acc[dt]);
                }
        }

        __syncthreads();   // drains staging gloads (vmcnt) + orders LDS reuse
    }

    // ---- normalize + store ----
    float invl = 1.f / l;
#pragma unroll
    for (int r = 0; r < 16; ++r) {
        float ir = __shfl(invl, (r & 3) + 8 * (r >> 2) + 4 * hi);
        long orow = rowbase + q0 + (r & 3) + 8 * (r >> 2) + 4 * hi;
#pragma unroll
        for (int dt = 0; dt < 2; ++dt)
            out[orow * Dd + h * HD + dt * 32 + ln31] = __float2bfloat16(acc[dt][r] * ir);
    }
}

extern "C" void kernel_launch(void* const* d_in, const int* in_sizes, int n_in,
                              void* d_out, int out_size, void* d_ws, size_t ws_size,
                              hipStream_t stream) {
    const float* x    = (const float*)d_in[0];
    const float* Wqkv = (const float*)d_in[1];
    const float* Wo_w = (const float*)d_in[2];
    const float* Wo_b = (const float*)d_in[3];
    float* out = (float*)d_out;

    const size_t MB = 1ull << 20;
    char* ws = (char*)d_ws;
    bf16* xb    = (bf16*)(ws);
    bf16* wqkvb = (bf16*)(ws + 16 * MB);
    bf16* wob   = (bf16*)(ws + 22 * MB);
    bf16* qkv   = (bf16*)(ws + 24 * MB);
    bf16* attnb = xb;

    cast_f32_bf16<<<8192, 256, 0, stream>>>(x, xb, Mrows * Dd / 4);
    cast_f32_bf16<<<3072, 256, 0, stream>>>(Wqkv, wqkvb, TD * Dd / 4);
    cast_f32_bf16<<<1024, 256, 0, stream>>>(Wo_w, wob, Dd * Dd / 4);

    gemm_bt<true><<<dim3(TD / 128, Mrows / 128), 256, 0, stream>>>(
        xb, wqkvb, qkv, nullptr, nullptr, Mrows, TD, Dd);

    attn_fwd4<<<dim3(16, Bb * Hh), 256, 0, stream>>>(qkv, attnb);

    gemm_bt<false><<<dim3(Dd / 128, Mrows / 128), 256, 0, stream>>>(
        attnb, wob, nullptr, out, Wo_b, Mrows, Dd, Dd);
}

// Round 6
// 193.007 us; speedup vs baseline: 1.0655x; 1.0655x over previous
//
#include <hip/hip_runtime.h>
#include <hip/hip_bf16.h>

using bf16 = __hip_bfloat16;
typedef __attribute__((ext_vector_type(8))) short bf16x8;
typedef __attribute__((ext_vector_type(4))) short bf16x4;
typedef __attribute__((ext_vector_type(4))) float f32x4;
typedef __attribute__((ext_vector_type(16))) float f32x16;

static constexpr int Bb = 4, Ss = 2048, Dd = 1024, Hh = 16, HD = 64;
static constexpr int TD = 3 * Dd;            // 3072
static constexpr int Mrows = Bb * Ss;        // 8192

#define MFMA16(a, b, c) __builtin_amdgcn_mfma_f32_16x16x32_bf16((a), (b), (c), 0, 0, 0)
#define MFMA32(a, b, c) __builtin_amdgcn_mfma_f32_32x32x16_bf16((a), (b), (c), 0, 0, 0)

__device__ __forceinline__ void gload_lds16(const void* g, void* l) {
    __builtin_amdgcn_global_load_lds(
        (const __attribute__((address_space(1))) void*)g,
        (__attribute__((address_space(3))) void*)l, 16, 0, 0);
}

__device__ __forceinline__ unsigned lds_addr(const void* p) {
    return (unsigned)(unsigned long long)(const __attribute__((address_space(3))) char*)p;
}

__device__ __forceinline__ unsigned pack2bf(float a, float b) {
    bf16 x = __float2bfloat16(a), y = __float2bfloat16(b);
    return (unsigned)(*(unsigned short*)&x) | ((unsigned)(*(unsigned short*)&y) << 16);
}

__device__ __forceinline__ float bf2f(short s) {
    unsigned u = ((unsigned)(unsigned short)s) << 16;
    return __builtin_bit_cast(float, u);
}

// ---------------- cast fp32 -> bf16, 4 elems/thread ----------------
__global__ void cast_f32_bf16(const float* __restrict__ in, bf16* __restrict__ out, int n4) {
    int i = blockIdx.x * blockDim.x + threadIdx.x;
    if (i >= n4) return;
    float4 v = ((const float4*)in)[i];
    bf16 t0 = __float2bfloat16(v.x), t1 = __float2bfloat16(v.y);
    bf16 t2 = __float2bfloat16(v.z), t3 = __float2bfloat16(v.w);
    unsigned int lo = (unsigned int)(*(unsigned short*)&t0) | ((unsigned int)(*(unsigned short*)&t1) << 16);
    unsigned int hi = (unsigned int)(*(unsigned short*)&t2) | ((unsigned int)(*(unsigned short*)&t3) << 16);
    uint2 o; o.x = lo; o.y = hi;
    *(uint2*)(out + 4l * i) = o;
}

// ---------------- GEMM: C[m,n] = sum_k A[m,k] * Bt[n,k] ----------------
// 128x128 tile, BK=32, 4 waves. XCD-aware bijective block swizzle (T1).
template<bool OUT_BF16>
__global__ __launch_bounds__(256, 2) void gemm_bt(
    const bf16* __restrict__ A, const bf16* __restrict__ Bt,
    bf16* __restrict__ Cb, float* __restrict__ Cf, const float* __restrict__ bias,
    int M, int N, int K)
{
    __shared__ __align__(16) bf16 As[128 * 32];
    __shared__ __align__(16) bf16 Bs[128 * 32];
    const int tid = threadIdx.x;
    const int lane = tid & 63, wid = tid >> 6;
    const int lc = lane & 15, lg = lane >> 4;
    const int wr = wid >> 1, wc = wid & 1;

    const int nwg = gridDim.x * gridDim.y;
    int orig = blockIdx.y * gridDim.x + blockIdx.x;
    int swz = orig;
    if ((nwg & 7) == 0) swz = (orig & 7) * (nwg >> 3) + (orig >> 3);
    const long tile_m = (long)(swz / (int)gridDim.x) * 128;
    const long tile_n = (long)(swz % (int)gridDim.x) * 128;

    const f32x4 fz = {0.f, 0.f, 0.f, 0.f};
    f32x4 acc[4][4];
#pragma unroll
    for (int i = 0; i < 4; ++i)
#pragma unroll
        for (int j = 0; j < 4; ++j) acc[i][j] = fz;

    for (int k0 = 0; k0 < K; k0 += 32) {
#pragma unroll
        for (int it = 0; it < 2; ++it) {
            int c = tid + it * 256;
            int row = c >> 2, seg = c & 3;
            gload_lds16(A  + (tile_m + row) * (long)K + k0 + seg * 8, (char*)As + c * 16);
            gload_lds16(Bt + (tile_n + row) * (long)K + k0 + seg * 8, (char*)Bs + c * 16);
        }
        __syncthreads();
        bf16x8 af[4], bfr[4];
#pragma unroll
        for (int i = 0; i < 4; ++i) {
            af[i]  = *(const bf16x8*)(As + (wr * 64 + i * 16 + lc) * 32 + lg * 8);
            bfr[i] = *(const bf16x8*)(Bs + (wc * 64 + i * 16 + lc) * 32 + lg * 8);
        }
#pragma unroll
        for (int i = 0; i < 4; ++i)
#pragma unroll
            for (int j = 0; j < 4; ++j)
                acc[i][j] = MFMA16(af[i], bfr[j], acc[i][j]);
        __syncthreads();
    }
#pragma unroll
    for (int i = 0; i < 4; ++i)
#pragma unroll
        for (int j = 0; j < 4; ++j)
#pragma unroll
            for (int r = 0; r < 4; ++r) {
                long row = tile_m + wr * 64 + i * 16 + lg * 4 + r;
                long col = tile_n + wc * 64 + j * 16 + lc;
                float v = acc[i][j][r];
                if constexpr (OUT_BF16) Cb[row * N + col] = __float2bfloat16(v);
                else                    Cf[row * N + col] = v + bias[col];
            }
}

// ---------------- causal flash attention v5: v3 pairing + split-K ----------
// grid: (8 pairs x 2 key-halves, B*H), 4 waves. Block handles q-strips
// (p, 15-p) of 128 rows over key-tile range [kb, ke); every wave computes
// one 32-row chunk of BOTH strips (v3's perfectly-balanced form). Partials
// (O/l, m2 log2-domain, l) written per half; attn_combine merges.
// K/V staged by global_load_lds (pre-swizzled source, linear LDS dest),
// double-buffered, 1 barrier/tile. (256,2): VGPR must stay <=128 naturally —
// a forced cap spills in-flight tr-read dests (round-4 lesson).
__global__ __launch_bounds__(256, 2) void attn_fwd5(const bf16* __restrict__ qkv,
                                                    bf16* __restrict__ O0,
                                                    bf16* __restrict__ O1,
                                                    float2* __restrict__ mlb) {
    const int p    = blockIdx.x >> 1;          // 0..7
    const int half = blockIdx.x & 1;
    const int bh = blockIdx.y;                 // 0..63
    const int b = bh >> 4, h = bh & 15;
    const int tid = threadIdx.x;
    const int lane = tid & 63, wid = tid >> 6;
    const int ln31 = lane & 31, hi = lane >> 5;
    const int ch = (lane >> 4) & 1, c16 = lane & 15;
    const long rowbase = (long)b * Ss;
    const int sA = p, sB = 15 - p;
    const int q0A = sA * 128 + wid * 32;
    const int q0B = sB * 128 + wid * 32;
    const int ntt = 2 * sB + 2;                // total tiles for this pair
    const int kb = half * (ntt >> 1);
    const int ke = kb + (ntt >> 1);
    const float CL2 = 0.18033688f;             // 0.125 * log2(e)

    __shared__ __align__(16) bf16 Ks[2][64 * 64];
    __shared__ __align__(16) bf16 Vs[2][64 * 64];

    // staging: LDS linear in slot s, global source pre-swizzled (G21 pattern)
    const int sK0 = tid, sK1 = tid + 256;
    const int rK0 = sK0 >> 3, cK0 = ((sK0 & 7) ^ (rK0 & 7)) * 8;
    const int rK1 = sK1 >> 3, cK1 = ((sK1 & 7) ^ (rK1 & 7)) * 8;
    const int rV0 = ((sK0 >> 5) << 2) | ((sK0 >> 1) & 3);
    const int cV0 = ((((sK0 >> 3) & 3) << 1) | (sK0 & 1)) * 8;
    const int rV1 = ((sK1 >> 5) << 2) | ((sK1 >> 1) & 3);
    const int cV1 = ((((sK1 >> 3) & 3) << 1) | (sK1 & 1)) * 8;
    const bf16* gK0 = qkv + (rowbase + rK0) * (long)TD + h * HD + Dd + cK0;
    const bf16* gK1 = qkv + (rowbase + rK1) * (long)TD + h * HD + Dd + cK1;
    const bf16* gV0 = qkv + (rowbase + rV0) * (long)TD + h * HD + 2 * Dd + cV0;
    const bf16* gV1 = qkv + (rowbase + rV1) * (long)TD + h * HD + 2 * Dd + cV1;

    auto STAGE = [&](int buf, int kt) {
        const long o = (long)kt * 64 * TD;
        gload_lds16(gK0 + o, (char*)Ks[buf] + tid * 16);
        gload_lds16(gK1 + o, (char*)Ks[buf] + 4096 + tid * 16);
        gload_lds16(gV0 + o, (char*)Vs[buf] + tid * 16);
        gload_lds16(gV1 + o, (char*)Vs[buf] + 4096 + tid * 16);
    };

    // Q fragments (B-operand of 32x32x16): qa[dk][i] = Q[q0+ln31][dk*16+hi*8+i]
    bf16x8 qaA[4], qaB[4];
#pragma unroll
    for (int dk = 0; dk < 4; ++dk) {
        qaA[dk] = *(const bf16x8*)(qkv + (rowbase + q0A + ln31) * (long)TD + h * HD + dk * 16 + hi * 8);
        qaB[dk] = *(const bf16x8*)(qkv + (rowbase + q0B + ln31) * (long)TD + h * HD + dk * 16 + hi * 8);
    }

    f32x16 accA[2], accB[2];                   // acc[dt]: O[q=crow(r,hi)][dt*32+ln31]
#pragma unroll
    for (int dt = 0; dt < 2; ++dt) { accA[dt] = (f32x16)0.0f; accB[dt] = (f32x16)0.0f; }
    float m2A = -3.0e38f, m2B = -3.0e38f;      // running max, log2 units
    float lA = 0.f, lB = 0.f;

    auto TILE = [&](int kt, int q0x, f32x16* acc, const bf16x8* qa,
                    float& m2, float& lsum, const char* kbp, const char* vbp) {
        // ---- QK^T swapped: sc[st][r] = S^T[k=kt*64+st*32+crow(r,hi)][q=q0x+ln31]
        f32x16 sc[2];
        __builtin_amdgcn_s_setprio(1);
#pragma unroll
        for (int st = 0; st < 2; ++st) {
            f32x16 z = (f32x16)0.0f;
            const int row = st * 32 + ln31;
            const int sw = (row & 7) << 4;
#pragma unroll
            for (int dk = 0; dk < 4; ++dk) {
                bf16x8 ka = *(const bf16x8*)(kbp + ((row * 128 + dk * 32 + hi * 16) ^ sw));
                z = MFMA32(ka, qa[dk], z);
            }
            sc[st] = z;
        }
        __builtin_amdgcn_s_setprio(0);
        // ---- causal mask (diag tile only) ----
        if (kt * 64 + 63 > q0x) {
            const int qg = q0x + ln31;
            const int kbase = kt * 64 + 4 * hi;
#pragma unroll
            for (int st = 0; st < 2; ++st)
#pragma unroll
                for (int r = 0; r < 16; ++r) {
                    int kg = kbase + st * 32 + (r & 3) + 8 * (r >> 2);
                    if (kg > qg) sc[st][r] = -3.0e38f;
                }
        }
        // ---- row max ----
        float mx = sc[0][0];
#pragma unroll
        for (int r = 1; r < 16; ++r) mx = fmaxf(mx, sc[0][r]);
#pragma unroll
        for (int r = 0; r < 16; ++r) mx = fmaxf(mx, sc[1][r]);
        mx = fmaxf(mx, __shfl_xor(mx, 32));
        float pmax2 = mx * CL2;
        // ---- defer-max rescale (rare) ----
        if (__ballot(pmax2 > m2 + 8.0f)) {
            float mnew = fmaxf(m2, pmax2);
            float sf = __builtin_amdgcn_exp2f(m2 - mnew);
            m2 = mnew;
            lsum *= sf;
#pragma unroll
            for (int r = 0; r < 16; ++r) {
                float sfr = __shfl(sf, (r & 3) + 8 * (r >> 2) + 4 * hi);
                acc[0][r] *= sfr;
                acc[1][r] *= sfr;
            }
        }
        // ---- issue all 16 V tr-reads early ----
        bf16x4 vl[4][2], vh[4][2];
        const unsigned vbase = lds_addr(vbp) + hi * 1024 + ch * 128 + c16 * 8;
#pragma unroll
        for (int ksg = 0; ksg < 4; ++ksg)
#pragma unroll
            for (int dt = 0; dt < 2; ++dt) {
                asm volatile("ds_read_b64_tr_b16 %0, %2\n\t"
                             "ds_read_b64_tr_b16 %1, %2 offset:512"
                             : "=v"(vl[ksg][dt]), "=v"(vh[ksg][dt])
                             : "v"(vbase + (unsigned)(ksg * 2048 + dt * 256)) : "memory");
            }
        // ---- exp + row-sum + pack ----
        const float mt = m2;
        float sum = 0.f;
        unsigned w[2][8];
#pragma unroll
        for (int st = 0; st < 2; ++st)
#pragma unroll
            for (int n = 0; n < 8; ++n) {
                float e0 = __builtin_amdgcn_exp2f(fmaf(sc[st][2 * n],     CL2, -mt));
                float e1 = __builtin_amdgcn_exp2f(fmaf(sc[st][2 * n + 1], CL2, -mt));
                sum += e0 + e1;
                w[st][n] = pack2bf(e0, e1);
            }
        sum += __shfl_xor(sum, 32);
        lsum += sum;
        // ---- P exchange: 8 permlane32_swap ----
        union { unsigned u[4]; bf16x8 v; } pa[4];
#pragma unroll
        for (int ksg = 0; ksg < 4; ++ksg) {
            const int st = ksg >> 1, kl = ksg & 1;
            unsigned x0 = w[st][4 * kl],     y0 = w[st][4 * kl + 2];
            unsigned x1 = w[st][4 * kl + 1], y1 = w[st][4 * kl + 3];
            asm volatile("v_permlane32_swap_b32 %0, %1" : "+v"(x0), "+v"(y0));
            asm volatile("v_permlane32_swap_b32 %0, %1" : "+v"(x1), "+v"(y1));
            pa[ksg].u[0] = x0; pa[ksg].u[1] = x1; pa[ksg].u[2] = y0; pa[ksg].u[3] = y1;
        }
        // ---- PV ----
        asm volatile("s_waitcnt lgkmcnt(0)" ::: "memory");
        __builtin_amdgcn_sched_barrier(0);
        __builtin_amdgcn_s_setprio(1);
#pragma unroll
        for (int ksg = 0; ksg < 4; ++ksg)
#pragma unroll
            for (int dt = 0; dt < 2; ++dt) {
                bf16x8 vb = __builtin_shufflevector(vl[ksg][dt], vh[ksg][dt],
                                                    0, 1, 2, 3, 4, 5, 6, 7);
                acc[dt] = MFMA32(pa[ksg].v, vb, acc[dt]);
            }
        __builtin_amdgcn_s_setprio(0);
    };

    STAGE(0, kb);
    __syncthreads();

    for (int kt = kb; kt < ke; ++kt) {
        const int cur = (kt - kb) & 1;
        if (kt + 1 < ke) STAGE(cur ^ 1, kt + 1);

        if (kt * 64 <= q0B + 31)
            TILE(kt, q0B, accB, qaB, m2B, lB, (const char*)Ks[cur], (const char*)Vs[cur]);
        if (kt * 64 <= q0A + 31)
            TILE(kt, q0A, accA, qaA, m2A, lA, (const char*)Ks[cur], (const char*)Vs[cur]);

        __syncthreads();   // drains staging gloads + orders LDS reuse
    }

    // ---- write partials: O/l (0 if empty), plus (m2, l) per row ----
    bf16* Op = half ? O1 : O0;
    auto EPI = [&](const f32x16* acc, float l, int q0x) {
        float invl = (l > 0.f) ? 1.f / l : 0.f;
#pragma unroll
        for (int r = 0; r < 16; ++r) {
            float ir = __shfl(invl, (r & 3) + 8 * (r >> 2) + 4 * hi);
            long orow = rowbase + q0x + (r & 3) + 8 * (r >> 2) + 4 * hi;
#pragma unroll
            for (int dt = 0; dt < 2; ++dt)
                Op[orow * Dd + h * HD + dt * 32 + ln31] = __float2bfloat16(acc[dt][r] * ir);
        }
    };
    EPI(accB, lB, q0B);
    EPI(accA, lA, q0A);
    if (hi == 0) {
        mlb[((long)half * Mrows + rowbase + q0B + ln31) * Hh + h] = make_float2(m2B, lB);
        mlb[((long)half * Mrows + rowbase + q0A + ln31) * Hh + h] = make_float2(m2A, lA);
    }
}

// ---------------- combine split-K partials ----------------
// out = (w0*O0 + w1*O1) / (w0+w1), wi = li * 2^(m2i - M).  In-place on O0.
__global__ void attn_combine(const bf16* __restrict__ O1,
                             const float2* __restrict__ mlb,
                             bf16* __restrict__ O0out) {
    int g = blockIdx.x * blockDim.x + threadIdx.x;  // 8192*128 groups of 8
    int row = g >> 7, c8 = g & 127;
    int h = c8 >> 3;
    float2 a0 = mlb[(long)row * Hh + h];
    float2 a1 = mlb[((long)Mrows + row) * Hh + h];
    float M = fmaxf(a0.x, a1.x);
    float w0 = a0.y * __builtin_amdgcn_exp2f(a0.x - M);
    float w1 = a1.y * __builtin_amdgcn_exp2f(a1.x - M);
    float inv = 1.f / (w0 + w1);
    w0 *= inv; w1 *= inv;
    bf16x8 v0 = *(const bf16x8*)(O0out + (long)g * 8);
    bf16x8 v1 = *(const bf16x8*)(O1   + (long)g * 8);
    unsigned res[4];
#pragma unroll
    for (int i = 0; i < 4; ++i) {
        float o0 = w0 * bf2f(v0[2 * i])     + w1 * bf2f(v1[2 * i]);
        float o1 = w0 * bf2f(v0[2 * i + 1]) + w1 * bf2f(v1[2 * i + 1]);
        res[i] = pack2bf(o0, o1);
    }
    *(uint4*)(O0out + (long)g * 8) = make_uint4(res[0], res[1], res[2], res[3]);
}

extern "C" void kernel_launch(void* const* d_in, const int* in_sizes, int n_in,
                              void* d_out, int out_size, void* d_ws, size_t ws_size,
                              hipStream_t stream) {
    const float* x    = (const float*)d_in[0];
    const float* Wqkv = (const float*)d_in[1];
    const float* Wo_w = (const float*)d_in[2];
    const float* Wo_b = (const float*)d_in[3];
    float* out = (float*)d_out;

    const size_t MB = 1ull << 20;
    char* ws = (char*)d_ws;
    bf16* xb    = (bf16*)(ws);               // 16 MB; later O-partial half0 + final attn
    bf16* wqkvb = (bf16*)(ws + 16 * MB);     // 6 MB (dead after GEMM1; ml reuses it)
    bf16* wob   = (bf16*)(ws + 22 * MB);     // 2 MB
    bf16* qkv   = (bf16*)(ws + 24 * MB);     // 48 MB
    bf16* Opart1 = (bf16*)(ws + 72 * MB);    // 16 MB
    float2* mlb  = (float2*)(ws + 16 * MB);  // 2 MB, overlaps dead wqkvb
    bf16* attnb = xb;

    cast_f32_bf16<<<8192, 256, 0, stream>>>(x, xb, Mrows * Dd / 4);
    cast_f32_bf16<<<3072, 256, 0, stream>>>(Wqkv, wqkvb, TD * Dd / 4);
    cast_f32_bf16<<<1024, 256, 0, stream>>>(Wo_w, wob, Dd * Dd / 4);

    gemm_bt<true><<<dim3(TD / 128, Mrows / 128), 256, 0, stream>>>(
        xb, wqkvb, qkv, nullptr, nullptr, Mrows, TD, Dd);

    attn_fwd5<<<dim3(16, Bb * Hh), 256, 0, stream>>>(qkv, attnb, Opart1, mlb);
    attn_combine<<<Mrows * 128 / 256, 256, 0, stream>>>(Opart1, mlb, attnb);

    gemm_bt<false><<<dim3(Dd / 128, Mrows / 128), 256, 0, stream>>>(
        attnb, wob, nullptr, out, Wo_b, Mrows, Dd, Dd);
}

// Round 7
// 165.214 us; speedup vs baseline: 1.2448x; 1.1682x over previous
//
#include <hip/hip_runtime.h>
#include <hip/hip_bf16.h>

using bf16 = __hip_bfloat16;
typedef __attribute__((ext_vector_type(8))) short bf16x8;
typedef __attribute__((ext_vector_type(4))) short bf16x4;
typedef __attribute__((ext_vector_type(4))) float f32x4;
typedef __attribute__((ext_vector_type(16))) float f32x16;

static constexpr int Bb = 4, Ss = 2048, Dd = 1024, Hh = 16, HD = 64;
static constexpr int TD = 3 * Dd;            // 3072
static constexpr int Mrows = Bb * Ss;        // 8192

#define MFMA16(a, b, c) __builtin_amdgcn_mfma_f32_16x16x32_bf16((a), (b), (c), 0, 0, 0)
#define MFMA32(a, b, c) __builtin_amdgcn_mfma_f32_32x32x16_bf16((a), (b), (c), 0, 0, 0)

__device__ __forceinline__ void gload_lds16(const void* g, void* l) {
    __builtin_amdgcn_global_load_lds(
        (const __attribute__((address_space(1))) void*)g,
        (__attribute__((address_space(3))) void*)l, 16, 0, 0);
}

__device__ __forceinline__ unsigned lds_addr(const void* p) {
    return (unsigned)(unsigned long long)(const __attribute__((address_space(3))) char*)p;
}

__device__ __forceinline__ unsigned pack2bf(float a, float b) {
    bf16 x = __float2bfloat16(a), y = __float2bfloat16(b);
    return (unsigned)(*(unsigned short*)&x) | ((unsigned)(*(unsigned short*)&y) << 16);
}

// ---------------- cast fp32 -> bf16, 4 elems/thread ----------------
__global__ void cast_f32_bf16(const float* __restrict__ in, bf16* __restrict__ out, int n4) {
    int i = blockIdx.x * blockDim.x + threadIdx.x;
    if (i >= n4) return;
    float4 v = ((const float4*)in)[i];
    bf16 t0 = __float2bfloat16(v.x), t1 = __float2bfloat16(v.y);
    bf16 t2 = __float2bfloat16(v.z), t3 = __float2bfloat16(v.w);
    unsigned int lo = (unsigned int)(*(unsigned short*)&t0) | ((unsigned int)(*(unsigned short*)&t1) << 16);
    unsigned int hi = (unsigned int)(*(unsigned short*)&t2) | ((unsigned int)(*(unsigned short*)&t3) << 16);
    uint2 o; o.x = lo; o.y = hi;
    *(uint2*)(out + 4l * i) = o;
}

// ---------------- GEMM: C[m,n] = sum_k A[m,k] * Bt[n,k] ----------------
// 128x128 tile, BK=32, 4 waves. XCD-aware bijective block swizzle (T1).
template<bool OUT_BF16>
__global__ __launch_bounds__(256, 2) void gemm_bt(
    const bf16* __restrict__ A, const bf16* __restrict__ Bt,
    bf16* __restrict__ Cb, float* __restrict__ Cf, const float* __restrict__ bias,
    int M, int N, int K)
{
    __shared__ __align__(16) bf16 As[128 * 32];
    __shared__ __align__(16) bf16 Bs[128 * 32];
    const int tid = threadIdx.x;
    const int lane = tid & 63, wid = tid >> 6;
    const int lc = lane & 15, lg = lane >> 4;
    const int wr = wid >> 1, wc = wid & 1;

    const int nwg = gridDim.x * gridDim.y;
    int orig = blockIdx.y * gridDim.x + blockIdx.x;
    int swz = orig;
    if ((nwg & 7) == 0) swz = (orig & 7) * (nwg >> 3) + (orig >> 3);
    const long tile_m = (long)(swz / (int)gridDim.x) * 128;
    const long tile_n = (long)(swz % (int)gridDim.x) * 128;

    const f32x4 fz = {0.f, 0.f, 0.f, 0.f};
    f32x4 acc[4][4];
#pragma unroll
    for (int i = 0; i < 4; ++i)
#pragma unroll
        for (int j = 0; j < 4; ++j) acc[i][j] = fz;

    for (int k0 = 0; k0 < K; k0 += 32) {
#pragma unroll
        for (int it = 0; it < 2; ++it) {
            int c = tid + it * 256;
            int row = c >> 2, seg = c & 3;
            gload_lds16(A  + (tile_m + row) * (long)K + k0 + seg * 8, (char*)As + c * 16);
            gload_lds16(Bt + (tile_n + row) * (long)K + k0 + seg * 8, (char*)Bs + c * 16);
        }
        __syncthreads();
        bf16x8 af[4], bfr[4];
#pragma unroll
        for (int i = 0; i < 4; ++i) {
            af[i]  = *(const bf16x8*)(As + (wr * 64 + i * 16 + lc) * 32 + lg * 8);
            bfr[i] = *(const bf16x8*)(Bs + (wc * 64 + i * 16 + lc) * 32 + lg * 8);
        }
#pragma unroll
        for (int i = 0; i < 4; ++i)
#pragma unroll
            for (int j = 0; j < 4; ++j)
                acc[i][j] = MFMA16(af[i], bfr[j], acc[i][j]);
        __syncthreads();
    }
#pragma unroll
    for (int i = 0; i < 4; ++i)
#pragma unroll
        for (int j = 0; j < 4; ++j)
#pragma unroll
            for (int r = 0; r < 4; ++r) {
                long row = tile_m + wr * 64 + i * 16 + lg * 4 + r;
                long col = tile_n + wc * 64 + j * 16 + lc;
                float v = acc[i][j][r];
                if constexpr (OUT_BF16) Cb[row * N + col] = __float2bfloat16(v);
                else                    Cf[row * N + col] = v + bias[col];
            }
}

// ---------------- causal flash attention v6: single strip, heavy-first ----
// grid: (bh=64, p=16), 4 waves. Block owns q-strip s=15-p (128 rows, waves
// take 32 each) over its full causal kv range nt=2s+2. Linear block id =
// p*64+bh -> id%8 = bh%8: all 16 strip-blocks of a head pin to ONE XCD
// (8 heads' K/V = 4MB = L2) and heaviest strips dispatch first so 4-5
// blocks/CU backfill absorbs the causal skew. Single-strip body = minimal
// persistent regs (v4b: VGPR 76) -> real co-residency, unlike v5's dual-strip.
// K/V staged by global_load_lds (pre-swizzled source, linear LDS dest),
// double-buffered, 1 barrier/tile. No forced VGPR cap (round-4 lesson).
__global__ __launch_bounds__(256, 2) void attn_fwd6(const bf16* __restrict__ qkv,
                                                    bf16* __restrict__ out) {
    const int bh = blockIdx.x;                 // 0..63
    const int p  = blockIdx.y;                 // 0..15
    const int s  = 15 - p;                     // strip index, heavy first
    const int b = bh >> 4, h = bh & 15;
    const int tid = threadIdx.x;
    const int lane = tid & 63, wid = tid >> 6;
    const int ln31 = lane & 31, hi = lane >> 5;
    const int ch = (lane >> 4) & 1, c16 = lane & 15;
    const long rowbase = (long)b * Ss;
    const int q0 = s * 128 + wid * 32;         // this wave's 32 q-rows
    const int nt = 2 * s + 2;                  // causal kv tiles
    const float CL2 = 0.18033688f;             // 0.125 * log2(e)

    __shared__ __align__(16) bf16 Ks[2][64 * 64];
    __shared__ __align__(16) bf16 Vs[2][64 * 64];

    // staging: LDS linear in slot, global source pre-swizzled (G21 pattern)
    const int sK0 = tid, sK1 = tid + 256;
    const int rK0 = sK0 >> 3, cK0 = ((sK0 & 7) ^ (rK0 & 7)) * 8;
    const int rK1 = sK1 >> 3, cK1 = ((sK1 & 7) ^ (rK1 & 7)) * 8;
    const int rV0 = ((sK0 >> 5) << 2) | ((sK0 >> 1) & 3);
    const int cV0 = ((((sK0 >> 3) & 3) << 1) | (sK0 & 1)) * 8;
    const int rV1 = ((sK1 >> 5) << 2) | ((sK1 >> 1) & 3);
    const int cV1 = ((((sK1 >> 3) & 3) << 1) | (sK1 & 1)) * 8;
    const bf16* gK0 = qkv + (rowbase + rK0) * (long)TD + h * HD + Dd + cK0;
    const bf16* gK1 = qkv + (rowbase + rK1) * (long)TD + h * HD + Dd + cK1;
    const bf16* gV0 = qkv + (rowbase + rV0) * (long)TD + h * HD + 2 * Dd + cV0;
    const bf16* gV1 = qkv + (rowbase + rV1) * (long)TD + h * HD + 2 * Dd + cV1;

    auto STAGE = [&](int buf, int kt) {
        const long o = (long)kt * 64 * TD;
        gload_lds16(gK0 + o, (char*)Ks[buf] + tid * 16);
        gload_lds16(gK1 + o, (char*)Ks[buf] + 4096 + tid * 16);
        gload_lds16(gV0 + o, (char*)Vs[buf] + tid * 16);
        gload_lds16(gV1 + o, (char*)Vs[buf] + 4096 + tid * 16);
    };

    // Q fragments (B-operand of 32x32x16): qa[dk][i] = Q[q0+ln31][dk*16+hi*8+i]
    bf16x8 qa[4];
#pragma unroll
    for (int dk = 0; dk < 4; ++dk)
        qa[dk] = *(const bf16x8*)(qkv + (rowbase + q0 + ln31) * (long)TD + h * HD + dk * 16 + hi * 8);

    f32x16 acc[2];                             // acc[dt]: O[q=crow(r,hi)][dt*32+ln31]
#pragma unroll
    for (int dt = 0; dt < 2; ++dt) acc[dt] = (f32x16)0.0f;
    float m2 = -3.0e38f;                       // running max, log2 units
    float l = 0.f;

    STAGE(0, 0);
    __syncthreads();

    for (int kt = 0; kt < nt; ++kt) {
        const int cur = kt & 1;
        if (kt + 1 < nt) STAGE(cur ^ 1, kt + 1);

        if (kt * 64 <= q0 + 31) {
            const char* kbp = (const char*)Ks[cur];
            const char* vbp = (const char*)Vs[cur];
            // ---- QK^T swapped: sc[st][r] = S^T[k=kt*64+st*32+crow(r,hi)][q=q0+ln31]
            f32x16 sc[2];
            __builtin_amdgcn_s_setprio(1);
#pragma unroll
            for (int st = 0; st < 2; ++st) {
                f32x16 z = (f32x16)0.0f;
                const int row = st * 32 + ln31;
                const int sw = (row & 7) << 4;
#pragma unroll
                for (int dk = 0; dk < 4; ++dk) {
                    bf16x8 ka = *(const bf16x8*)(kbp + ((row * 128 + dk * 32 + hi * 16) ^ sw));
                    z = MFMA32(ka, qa[dk], z);
                }
                sc[st] = z;
            }
            __builtin_amdgcn_s_setprio(0);
            // ---- causal mask (diag tile only) ----
            if (kt * 64 + 63 > q0) {
                const int qg = q0 + ln31;
                const int kbase = kt * 64 + 4 * hi;
#pragma unroll
                for (int st = 0; st < 2; ++st)
#pragma unroll
                    for (int r = 0; r < 16; ++r) {
                        int kg = kbase + st * 32 + (r & 3) + 8 * (r >> 2);
                        if (kg > qg) sc[st][r] = -3.0e38f;
                    }
            }
            // ---- row max ----
            float mx = sc[0][0];
#pragma unroll
            for (int r = 1; r < 16; ++r) mx = fmaxf(mx, sc[0][r]);
#pragma unroll
            for (int r = 0; r < 16; ++r) mx = fmaxf(mx, sc[1][r]);
            mx = fmaxf(mx, __shfl_xor(mx, 32));
            float pmax2 = mx * CL2;
            // ---- defer-max rescale (rare) ----
            if (__ballot(pmax2 > m2 + 8.0f)) {
                float mnew = fmaxf(m2, pmax2);
                float sf = __builtin_amdgcn_exp2f(m2 - mnew);
                m2 = mnew;
                l *= sf;
#pragma unroll
                for (int r = 0; r < 16; ++r) {
                    float sfr = __shfl(sf, (r & 3) + 8 * (r >> 2) + 4 * hi);
                    acc[0][r] *= sfr;
                    acc[1][r] *= sfr;
                }
            }
            // ---- issue all 16 V tr-reads early ----
            bf16x4 vl[4][2], vh[4][2];
            const unsigned vbase = lds_addr(vbp) + hi * 1024 + ch * 128 + c16 * 8;
#pragma unroll
            for (int ksg = 0; ksg < 4; ++ksg)
#pragma unroll
                for (int dt = 0; dt < 2; ++dt) {
                    asm volatile("ds_read_b64_tr_b16 %0, %2\n\t"
                                 "ds_read_b64_tr_b16 %1, %2 offset:512"
                                 : "=v"(vl[ksg][dt]), "=v"(vh[ksg][dt])
                                 : "v"(vbase + (unsigned)(ksg * 2048 + dt * 256)) : "memory");
                }
            // ---- exp + row-sum + pack ----
            const float mt = m2;
            float sum = 0.f;
            unsigned w[2][8];
#pragma unroll
            for (int st = 0; st < 2; ++st)
#pragma unroll
                for (int n = 0; n < 8; ++n) {
                    float e0 = __builtin_amdgcn_exp2f(fmaf(sc[st][2 * n],     CL2, -mt));
                    float e1 = __builtin_amdgcn_exp2f(fmaf(sc[st][2 * n + 1], CL2, -mt));
                    sum += e0 + e1;
                    w[st][n] = pack2bf(e0, e1);
                }
            sum += __shfl_xor(sum, 32);
            l += sum;
            // ---- P exchange: 8 permlane32_swap ----
            union { unsigned u[4]; bf16x8 v; } pa[4];
#pragma unroll
            for (int ksg = 0; ksg < 4; ++ksg) {
                const int st = ksg >> 1, kl = ksg & 1;
                unsigned x0 = w[st][4 * kl],     y0 = w[st][4 * kl + 2];
                unsigned x1 = w[st][4 * kl + 1], y1 = w[st][4 * kl + 3];
                asm volatile("v_permlane32_swap_b32 %0, %1" : "+v"(x0), "+v"(y0));
                asm volatile("v_permlane32_swap_b32 %0, %1" : "+v"(x1), "+v"(y1));
                pa[ksg].u[0] = x0; pa[ksg].u[1] = x1; pa[ksg].u[2] = y0; pa[ksg].u[3] = y1;
            }
            // ---- PV ----
            asm volatile("s_waitcnt lgkmcnt(0)" ::: "memory");
            __builtin_amdgcn_sched_barrier(0);
            __builtin_amdgcn_s_setprio(1);
#pragma unroll
            for (int ksg = 0; ksg < 4; ++ksg)
#pragma unroll
                for (int dt = 0; dt < 2; ++dt) {
                    bf16x8 vb = __builtin_shufflevector(vl[ksg][dt], vh[ksg][dt],
                                                        0, 1, 2, 3, 4, 5, 6, 7);
                    acc[dt] = MFMA32(pa[ksg].v, vb, acc[dt]);
                }
            __builtin_amdgcn_s_setprio(0);
        }

        __syncthreads();   // drains staging gloads + orders LDS reuse
    }

    // ---- normalize + store ----
    float invl = 1.f / l;
#pragma unroll
    for (int r = 0; r < 16; ++r) {
        float ir = __shfl(invl, (r & 3) + 8 * (r >> 2) + 4 * hi);
        long orow = rowbase + q0 + (r & 3) + 8 * (r >> 2) + 4 * hi;
#pragma unroll
        for (int dt = 0; dt < 2; ++dt)
            out[orow * Dd + h * HD + dt * 32 + ln31] = __float2bfloat16(acc[dt][r] * ir);
    }
}

extern "C" void kernel_launch(void* const* d_in, const int* in_sizes, int n_in,
                              void* d_out, int out_size, void* d_ws, size_t ws_size,
                              hipStream_t stream) {
    const float* x    = (const float*)d_in[0];
    const float* Wqkv = (const float*)d_in[1];
    const float* Wo_w = (const float*)d_in[2];
    const float* Wo_b = (const float*)d_in[3];
    float* out = (float*)d_out;

    const size_t MB = 1ull << 20;
    char* ws = (char*)d_ws;
    bf16* xb    = (bf16*)(ws);               // 16 MB; reused as attn output
    bf16* wqkvb = (bf16*)(ws + 16 * MB);     // 6 MB
    bf16* wob   = (bf16*)(ws + 22 * MB);     // 2 MB
    bf16* qkv   = (bf16*)(ws + 24 * MB);     // 48 MB
    bf16* attnb = xb;

    cast_f32_bf16<<<8192, 256, 0, stream>>>(x, xb, Mrows * Dd / 4);
    cast_f32_bf16<<<3072, 256, 0, stream>>>(Wqkv, wqkvb, TD * Dd / 4);
    cast_f32_bf16<<<1024, 256, 0, stream>>>(Wo_w, wob, Dd * Dd / 4);

    gemm_bt<true><<<dim3(TD / 128, Mrows / 128), 256, 0, stream>>>(
        xb, wqkvb, qkv, nullptr, nullptr, Mrows, TD, Dd);

    attn_fwd6<<<dim3(Bb * Hh, 16), 256, 0, stream>>>(qkv, attnb);

    gemm_bt<false><<<dim3(Dd / 128, Mrows / 128), 256, 0, stream>>>(
        attnb, wob, nullptr, out, Wo_b, Mrows, Dd, Dd);
}